// Round 1
// baseline (88.811 us; speedup 1.0000x reference)
//
#include <hip/hip_runtime.h>
#include <math.h>

#define NCELLS 20
#define INDIM  8
#define HID    10

__device__ __forceinline__ float sigmoidf_(float v) {
    return 1.0f / (1.0f + __expf(-v));
}

// One block does the whole net: 20 LSTM cells (one step) + 200->50->10->1 MLP.
__global__ __launch_bounds__(256) void net_fused(
    const float* __restrict__ x,     // [8]
    const float* __restrict__ h0,    // [20,10]
    const float* __restrict__ c0,    // [20,10]
    const float* __restrict__ W_ih,  // [20,40,8]
    const float* __restrict__ W_hh,  // [20,40,10]
    const float* __restrict__ b_ih,  // [20,40]
    const float* __restrict__ b_hh,  // [20,40]
    const float* __restrict__ W1,    // [50,200]
    const float* __restrict__ b1,    // [50]
    const float* __restrict__ W2,    // [10,50]
    const float* __restrict__ b2,    // [10]
    const float* __restrict__ W3,    // [1,10]
    const float* __restrict__ b3,    // [1]
    float* __restrict__ out)         // [1]
{
    __shared__ float s_gates[NCELLS * 4 * HID];  // 800, activated gates
    __shared__ float s_feat[200];                // concat(h[10:], h[:10])
    __shared__ float s_h1[50];
    __shared__ float s_h2[10];

    const int tid = threadIdx.x;

    // x is shared by every gate: load once into registers (broadcast L1 hits).
    float xr[INDIM];
    #pragma unroll
    for (int i = 0; i < INDIM; ++i) xr[i] = x[i];

    // ---- Phase 1: 800 gates = W_ih@x + W_hh@h0 + b_ih + b_hh, activated ----
    for (int g = tid; g < NCELLS * 4 * HID; g += 256) {
        const int k = g / (4 * HID);         // cell
        const int r = g - k * (4 * HID);     // row within cell: 0..39
        float acc = b_ih[g] + b_hh[g];
        const float* wi = W_ih + g * INDIM;
        #pragma unroll
        for (int i = 0; i < INDIM; ++i) acc = fmaf(wi[i], xr[i], acc);
        const float* wh = W_hh + g * HID;
        const float* hh = h0 + k * HID;
        #pragma unroll
        for (int j = 0; j < HID; ++j) acc = fmaf(wh[j], hh[j], acc);
        const int gt = r / HID;              // 0:i 1:f 2:g 3:o (PyTorch order)
        s_gates[g] = (gt == 2) ? tanhf(acc) : sigmoidf_(acc);
    }
    __syncthreads();

    // ---- Phase 2: c = f*c0 + i*g ; h = o*tanh(c) ; scatter into feat ----
    if (tid < NCELLS * HID) {                // 200
        const int k = tid / HID, j = tid - k * HID;
        const float* gk = s_gates + k * (4 * HID);
        const float ig = gk[j];
        const float fg = gk[HID + j];
        const float gg = gk[2 * HID + j];
        const float og = gk[3 * HID + j];
        const float c  = fmaf(fg, c0[tid], ig * gg);
        const float h  = og * tanhf(c);
        // feat = concat(h[10:].flat, h[:10].flat)
        const int pos = (k >= 10) ? (k - 10) * HID + j : 100 + k * HID + j;
        s_feat[pos] = h;
    }
    __syncthreads();

    // ---- Phase 3: h1 = tanh(W1 @ feat + b1)  (50 outputs, 4 lanes each) ----
    if (tid < 200) {
        const int o = tid >> 2;              // output 0..49
        const int p = tid & 3;               // part 0..3
        float acc = 0.0f;
        const float* w = W1 + o * 200;
        for (int i = p; i < 200; i += 4) acc = fmaf(w[i], s_feat[i], acc);
        // reduce across the 4 lanes of this output (groups are wave-aligned)
        acc += __shfl_down(acc, 2, 4);
        acc += __shfl_down(acc, 1, 4);
        if (p == 0) s_h1[o] = tanhf(acc + b1[o]);
    }
    __syncthreads();

    // ---- Phase 4: h2 = tanh(W2 @ h1 + b2)  (10 outputs, serial 50-dots) ----
    if (tid < 10) {
        float acc = b2[tid];
        const float* w = W2 + tid * 50;
        #pragma unroll 10
        for (int i = 0; i < 50; ++i) acc = fmaf(w[i], s_h1[i], acc);
        s_h2[tid] = tanhf(acc);
    }
    __syncthreads();

    // ---- Phase 5: out = tanh(W3 @ h2 + b3) ----
    if (tid == 0) {
        float acc = b3[0];
        #pragma unroll
        for (int i = 0; i < 10; ++i) acc = fmaf(W3[i], s_h2[i], acc);
        out[0] = tanhf(acc);
    }
}

extern "C" void kernel_launch(void* const* d_in, const int* in_sizes, int n_in,
                              void* d_out, int out_size, void* d_ws, size_t ws_size,
                              hipStream_t stream) {
    const float* x    = (const float*)d_in[0];
    const float* h0   = (const float*)d_in[1];
    const float* c0   = (const float*)d_in[2];
    const float* W_ih = (const float*)d_in[3];
    const float* W_hh = (const float*)d_in[4];
    const float* b_ih = (const float*)d_in[5];
    const float* b_hh = (const float*)d_in[6];
    const float* W1   = (const float*)d_in[7];
    const float* b1   = (const float*)d_in[8];
    const float* W2   = (const float*)d_in[9];
    const float* b2   = (const float*)d_in[10];
    const float* W3   = (const float*)d_in[11];
    const float* b3   = (const float*)d_in[12];
    float* out = (float*)d_out;

    net_fused<<<1, 256, 0, stream>>>(x, h0, c0, W_ih, W_hh, b_ih, b_hh,
                                     W1, b1, W2, b2, W3, b3, out);
}

// Round 3
// 81.789 us; speedup vs baseline: 1.0859x; 1.0859x over previous
//
#include <hip/hip_runtime.h>
#include <math.h>

#define NCELLS 20
#define INDIM  8
#define HID    10
#define NGATES (NCELLS * 4 * HID)   // 800
#define W1PAD  204                  // padded row stride (floats); 204%4==0 keeps
                                    // 16B ds alignment, 204%32==12 → ~2-way banks

__device__ __forceinline__ float sigmoidf_(float v) {
    return 1.0f / (1.0f + __expf(-v));
}

// Single block does the whole net. Waves 0-1: LSTM gates. Waves 2-3: prefetch
// the decoder weights global->reg->LDS, overlapped with the gate compute, so
// no phase after the first barrier ever waits on a cold global load.
__global__ __launch_bounds__(256) void net_fused(
    const float* __restrict__ x,     // [8]
    const float* __restrict__ h0,    // [20,10]
    const float* __restrict__ c0,    // [20,10]
    const float* __restrict__ W_ih,  // [20,40,8]
    const float* __restrict__ W_hh,  // [20,40,10]
    const float* __restrict__ b_ih,  // [20,40]
    const float* __restrict__ b_hh,  // [20,40]
    const float* __restrict__ W1,    // [50,200]
    const float* __restrict__ b1,    // [50]
    const float* __restrict__ W2,    // [10,50]
    const float* __restrict__ b2,    // [10]
    const float* __restrict__ W3,    // [1,10]
    const float* __restrict__ b3,    // [1]
    float* __restrict__ out)         // [1]
{
    __shared__ float s_W1[50 * W1PAD];           // 40.8 KB, padded rows
    __shared__ float s_W2[500];
    __shared__ float s_gates[NGATES];            // activated gates
    __shared__ float s_feat[200];                // concat(h[10:], h[:10])
    __shared__ float s_h1[50];
    __shared__ float s_h2[10];
    __shared__ float s_b1[50];
    __shared__ float s_b2[10];
    __shared__ float s_w3[10];
    __shared__ float s_b3[1];

    const int tid = threadIdx.x;

    // Prefetch c0 for phase 2 (in flight during phase 1).
    const float c0r = (tid < NCELLS * HID) ? c0[tid] : 0.0f;

    if (tid < 128) {
        // ---- Waves 0-1: Phase 1 — 800 gates, 6-7 per thread ----
        float xr[INDIM];
        #pragma unroll
        for (int i = 0; i < INDIM; ++i) xr[i] = x[i];

        for (int g = tid; g < NGATES; g += 128) {
            const int k = g / (4 * HID);         // cell
            const int r = g - k * (4 * HID);     // row in cell 0..39
            float acc = b_ih[g] + b_hh[g];
            const float4 wi0 = *(const float4*)(W_ih + g * INDIM);
            const float4 wi1 = *(const float4*)(W_ih + g * INDIM + 4);
            acc = fmaf(wi0.x, xr[0], acc);
            acc = fmaf(wi0.y, xr[1], acc);
            acc = fmaf(wi0.z, xr[2], acc);
            acc = fmaf(wi0.w, xr[3], acc);
            acc = fmaf(wi1.x, xr[4], acc);
            acc = fmaf(wi1.y, xr[5], acc);
            acc = fmaf(wi1.z, xr[6], acc);
            acc = fmaf(wi1.w, xr[7], acc);
            const float* wh = W_hh + g * HID;
            const float* hh = h0 + k * HID;
            #pragma unroll
            for (int j = 0; j < HID; ++j) acc = fmaf(wh[j], hh[j], acc);
            const int gt = r / HID;              // 0:i 1:f 2:g 3:o
            s_gates[g] = (gt == 2) ? tanhf(acc) : sigmoidf_(acc);
        }
    } else {
        // ---- Waves 2-3: prefetch decoder params (issue-early / write-late) ----
        const int l = tid - 128;                 // 0..127
        const float4* w1v = (const float4*)W1;   // 2500 chunks of 4 floats

        float4 w1buf[20];
        #pragma unroll
        for (int j = 0; j < 19; ++j) w1buf[j] = w1v[l + 128 * j];
        const bool extra = (l + 2432) < 2500;    // l < 68
        if (extra) w1buf[19] = w1v[l + 2432];

        const bool hasw2 = l < 125;
        float4 w2buf;
        if (hasw2) w2buf = ((const float4*)W2)[l];

        float smallv = 0.0f;
        if (l < 50)                smallv = b1[l];
        else if (l < 60)           smallv = b2[l - 50];
        else if (l < 70)           smallv = W3[l - 60];
        else if (l == 70)          smallv = b3[0];

        // Writes drain as loads return; overlaps waves 0-1's gate compute.
        #pragma unroll
        for (int j = 0; j < 19; ++j) {
            const int m = l + 128 * j;
            const int row = m / 50;
            const int col = (m - row * 50) * 4;
            *(float4*)&s_W1[row * W1PAD + col] = w1buf[j];
        }
        if (extra) {
            const int m = l + 2432;
            const int row = m / 50;
            const int col = (m - row * 50) * 4;
            *(float4*)&s_W1[row * W1PAD + col] = w1buf[19];
        }
        if (hasw2) *(float4*)&s_W2[l * 4] = w2buf;
        if (l < 50)       s_b1[l] = smallv;
        else if (l < 60)  s_b2[l - 50] = smallv;
        else if (l < 70)  s_w3[l - 60] = smallv;
        else if (l == 70) s_b3[0] = smallv;
    }
    __syncthreads();

    // ---- Phase 2: c = f*c0 + i*g ; h = o*tanh(c) ; scatter into feat ----
    if (tid < NCELLS * HID) {                    // 200
        const int k = tid / HID, j = tid - k * HID;
        const float* gk = s_gates + k * (4 * HID);
        const float ig = gk[j];
        const float fg = gk[HID + j];
        const float gg = gk[2 * HID + j];
        const float og = gk[3 * HID + j];
        const float c  = fmaf(fg, c0r, ig * gg);
        const float h  = og * tanhf(c);
        const int pos = (k >= 10) ? (k - 10) * HID + j : 100 + k * HID + j;
        s_feat[pos] = h;
    }
    __syncthreads();

    // ---- Phase 3: h1 = tanh(W1 @ feat + b1)  (50 outputs x 4 lanes) ----
    if (tid < 200) {
        const int o = tid >> 2;
        const int p = tid & 3;
        const float* w = s_W1 + o * W1PAD;
        float acc = 0.0f;
        #pragma unroll
        for (int i = p; i < 200; i += 4) acc = fmaf(w[i], s_feat[i], acc);
        acc += __shfl_down(acc, 2, 4);
        acc += __shfl_down(acc, 1, 4);
        if (p == 0) s_h1[o] = tanhf(acc + s_b1[o]);
    }
    __syncthreads();

    // ---- Phase 4: h2 = tanh(W2 @ h1 + b2) ----
    if (tid < 10) {
        float acc = s_b2[tid];
        const float* w = s_W2 + tid * 50;
        #pragma unroll
        for (int i = 0; i < 50; ++i) acc = fmaf(w[i], s_h1[i], acc);
        s_h2[tid] = tanhf(acc);
    }
    __syncthreads();

    // ---- Phase 5: out = tanh(W3 @ h2 + b3) ----
    if (tid == 0) {
        float acc = s_b3[0];
        #pragma unroll
        for (int i = 0; i < 10; ++i) acc = fmaf(s_w3[i], s_h2[i], acc);
        out[0] = tanhf(acc);
    }
}

extern "C" void kernel_launch(void* const* d_in, const int* in_sizes, int n_in,
                              void* d_out, int out_size, void* d_ws, size_t ws_size,
                              hipStream_t stream) {
    const float* x    = (const float*)d_in[0];
    const float* h0   = (const float*)d_in[1];
    const float* c0   = (const float*)d_in[2];
    const float* W_ih = (const float*)d_in[3];
    const float* W_hh = (const float*)d_in[4];
    const float* b_ih = (const float*)d_in[5];
    const float* b_hh = (const float*)d_in[6];
    const float* W1   = (const float*)d_in[7];
    const float* b1   = (const float*)d_in[8];
    const float* W2   = (const float*)d_in[9];
    const float* b2   = (const float*)d_in[10];
    const float* W3   = (const float*)d_in[11];
    const float* b3   = (const float*)d_in[12];
    float* out = (float*)d_out;

    net_fused<<<1, 256, 0, stream>>>(x, h0, c0, W_ih, W_hh, b_ih, b_hh,
                                     W1, b1, W2, b2, W3, b3, out);
}